// Round 1
// 890.608 us; speedup vs baseline: 1.1256x; 1.1256x over previous
//
#include <hip/hip_runtime.h>

#define N_NODES 50000
#define HDIM 64
#define E_EDGES 800000
#define SCAN_BLK 1024
#define NPART ((N_NODES + SCAN_BLK - 1) / SCAN_BLK)   // 49
#define CHUNK 128
#define SEG_WAVES ((E_EDGES + CHUNK - 1) / CHUNK)     // 6250

__device__ __forceinline__ float lane_bcast(float v, int l) {
    return __int_as_float(__builtin_amdgcn_readlane(__float_as_int(v), l));
}

// ---------------- CSR build: histogram -> hierarchical scan -> scatter ---

__global__ void __launch_bounds__(256) hist_kernel(
        const int* __restrict__ dst1, const int* __restrict__ dst2,
        int* __restrict__ cnt1, int* __restrict__ cnt2) {
    const int* dst = blockIdx.y ? dst2 : dst1;
    int* cnt       = blockIdx.y ? cnt2 : cnt1;
    int e = blockIdx.x * 256 + threadIdx.x;
    if (e < E_EDGES) atomicAdd(&cnt[dst[e]], 1);
}

// per-1024-chunk partial sums (coalesced), grid (NPART, 2)
__global__ void __launch_bounds__(SCAN_BLK) partial_kernel(
        const int* __restrict__ cnt1, const int* __restrict__ cnt2,
        int* __restrict__ part) {
    const int* cnt = blockIdx.y ? cnt2 : cnt1;
    __shared__ int red[16];
    const int t = blockIdx.x * SCAN_BLK + threadIdx.x;
    int v = (t < N_NODES) ? cnt[t] : 0;
#pragma unroll
    for (int s = 32; s >= 1; s >>= 1) v += __shfl_xor(v, s);
    if ((threadIdx.x & 63) == 0) red[threadIdx.x >> 6] = v;
    __syncthreads();
    if (threadIdx.x == 0) {
        int ssum = 0;
#pragma unroll
        for (int i = 0; i < 16; ++i) ssum += red[i];
        part[blockIdx.y * NPART + blockIdx.x] = ssum;
    }
}

// exclusive scan of the NPART partials per relation; grid (1,2), 64 threads
__global__ void __launch_bounds__(64) scanp_kernel(
        const int* __restrict__ part, int* __restrict__ pofs) {
    const int r = blockIdx.y;
    const int t = threadIdx.x;
    int v = (t < NPART) ? part[r * NPART + t] : 0;
    const int orig = v;
#pragma unroll
    for (int s = 1; s < 64; s <<= 1) {
        int u = __shfl_up(v, s);
        if (t >= s) v += u;
    }
    if (t < NPART) pofs[r * NPART + t] = v - orig;   // exclusive prefix
}

// per-chunk scan + global offset; writes off and cur; grid (NPART, 2)
__global__ void __launch_bounds__(SCAN_BLK) fill_kernel(
        const int* __restrict__ cnt1, const int* __restrict__ cnt2,
        const int* __restrict__ pofs,
        int* __restrict__ off1, int* __restrict__ off2,
        int* __restrict__ cur1, int* __restrict__ cur2) {
    const int* cnt = blockIdx.y ? cnt2 : cnt1;
    int* off       = blockIdx.y ? off2 : off1;
    int* cur       = blockIdx.y ? cur2 : cur1;

    __shared__ int lds[SCAN_BLK];
    const int t = threadIdx.x;
    const int gid = blockIdx.x * SCAN_BLK + t;
    const int c = (gid < N_NODES) ? cnt[gid] : 0;
    lds[t] = c;
    __syncthreads();
    for (int s = 1; s < SCAN_BLK; s <<= 1) {
        int v = (t >= s) ? lds[t - s] : 0;
        __syncthreads();
        lds[t] += v;
        __syncthreads();
    }
    const int excl = lds[t] - c + pofs[blockIdx.y * NPART + blockIdx.x];
    if (gid < N_NODES) { off[gid] = excl; cur[gid] = excl; }
    if (gid == 0 && blockIdx.x == 0) off[N_NODES] = E_EDGES;
}

__global__ void __launch_bounds__(256) scatter_kernel(
        const int* __restrict__ src1, const int* __restrict__ dst1,
        const int* __restrict__ src2, const int* __restrict__ dst2,
        int* __restrict__ cur1, int* __restrict__ cur2,
        int2* __restrict__ pairs1, int2* __restrict__ pairs2) {
    const int* src = blockIdx.y ? src2 : src1;
    const int* dst = blockIdx.y ? dst2 : dst1;
    int* cur       = blockIdx.y ? cur2 : cur1;
    int2* pairs    = blockIdx.y ? pairs2 : pairs1;
    int e = blockIdx.x * 256 + threadIdx.x;
    if (e >= E_EDGES) return;
    int pos = atomicAdd(&cur[dst[e]], 1);
    pairs[pos] = make_int2(src[e], e);
}

// ---------------- aggregation: balanced node-aligned segmented reduce ----
// Wave w owns all nodes n with off[n] in [w*CHUNK, (w+1)*CHUNK) and
// processes each node's FULL edge list (may run past the chunk end).
// Exactly-once plain stores; no atomics; no memset. lane = column.

__global__ void __launch_bounds__(256) agg_seg_kernel(
        const float* __restrict__ h,
        const float* __restrict__ feat1, const float* __restrict__ feat2,
        const int* __restrict__ off1, const int* __restrict__ off2,
        const int2* __restrict__ pairs1, const int2* __restrict__ pairs2,
        float* __restrict__ a1, float* __restrict__ a2) {
    const float* feat = blockIdx.y ? feat2  : feat1;
    const int* off    = blockIdx.y ? off2   : off1;
    const int2* pairs = blockIdx.y ? pairs2 : pairs1;
    float* agg        = blockIdx.y ? a2     : a1;

    const int lane = threadIdx.x & 63;
    const int wv = blockIdx.x * 4 + (threadIdx.x >> 6);
    if (wv >= SEG_WAVES) return;

    const int C0 = wv * CHUNK;
    int C1 = C0 + CHUNK;
    if (C1 >= E_EDGES) C1 = E_EDGES + 1;   // last wave also owns trailing deg-0 nodes

    // first node whose segment starts at/after C0 (wave-uniform binary search)
    int lo = 0, hi = N_NODES;
    while (lo < hi) {
        int mid = (lo + hi) >> 1;
        if (off[mid] < C0) lo = mid + 1; else hi = mid;
    }
    int n = lo;
    if (n >= N_NODES) return;

    int s = off[n];
    while (s >= C0 && s < C1) {
        const int e = off[n + 1];
        float acc = 0.f;
        int i = s;
        for (; i + 4 <= e; i += 4) {
            int2 p0 = pairs[i];
            int2 p1 = pairs[i + 1];
            int2 p2 = pairs[i + 2];
            int2 p3 = pairs[i + 3];
            const float f0 = feat[((size_t)__builtin_amdgcn_readfirstlane(p0.y) << 6) + lane];
            const float g0 = h   [((size_t)__builtin_amdgcn_readfirstlane(p0.x) << 6) + lane];
            const float f1 = feat[((size_t)__builtin_amdgcn_readfirstlane(p1.y) << 6) + lane];
            const float g1 = h   [((size_t)__builtin_amdgcn_readfirstlane(p1.x) << 6) + lane];
            const float f2 = feat[((size_t)__builtin_amdgcn_readfirstlane(p2.y) << 6) + lane];
            const float g2 = h   [((size_t)__builtin_amdgcn_readfirstlane(p2.x) << 6) + lane];
            const float f3 = feat[((size_t)__builtin_amdgcn_readfirstlane(p3.y) << 6) + lane];
            const float g3 = h   [((size_t)__builtin_amdgcn_readfirstlane(p3.x) << 6) + lane];
            acc = fmaf(f0, g0, acc);
            acc = fmaf(f1, g1, acc);
            acc = fmaf(f2, g2, acc);
            acc = fmaf(f3, g3, acc);
        }
        for (; i < e; ++i) {
            int2 p = pairs[i];
            const float f = feat[((size_t)__builtin_amdgcn_readfirstlane(p.y) << 6) + lane];
            const float g = h   [((size_t)__builtin_amdgcn_readfirstlane(p.x) << 6) + lane];
            acc = fmaf(f, g, acc);
        }
        agg[((size_t)n << 6) + lane] = acc;
        if (++n >= N_NODES) break;
        s = e;   // off[n] == previous off[n+1]
    }
}

// ---------------- fused linear + relu + residual (readlane, W in VGPRs) --

__global__ void __launch_bounds__(256, 2) mlp_kernel(
        const float* __restrict__ h_in,
        const float* __restrict__ a1,
        const float* __restrict__ a2,
        const float* __restrict__ W,
        const float* __restrict__ b,
        float* __restrict__ h_out) {
    const int lane = threadIdx.x & 63;

    float w1r[HDIM], w2r[HDIM];          // W[k][lane] — 128 VGPRs, static idx
#pragma unroll
    for (int k = 0; k < HDIM; ++k) w1r[k] = W[k * HDIM + lane];
#pragma unroll
    for (int k = 0; k < HDIM; ++k) w2r[k] = W[(HDIM + k) * HDIM + lane];
    const float bias = b[lane];

    const int wv = blockIdx.x * 4 + (threadIdx.x >> 6);
    const int stride = gridDim.x * 4;
    for (int node = wv; node < N_NODES; node += stride) {
        const size_t base = (size_t)node << 6;
        const float x1 = a1[base + lane];
        const float x2 = a2[base + lane];
        float acc1 = bias, acc2 = 0.f;
#pragma unroll
        for (int k = 0; k < HDIM; ++k) {
            acc1 = fmaf(lane_bcast(x1, k), w1r[k], acc1);   // two independent
            acc2 = fmaf(lane_bcast(x2, k), w2r[k], acc2);   // fma chains
        }
        const float r = acc1 + acc2;
        h_out[base + lane] = h_in[base + lane] + fmaxf(r, 0.f);
    }
}

// ---------------- fallback (atomic path, if ws too small) ----------------

__global__ void __launch_bounds__(256) agg_atomic_kernel(
        const float* __restrict__ h,
        const float* __restrict__ feat,
        const int* __restrict__ src,
        const int* __restrict__ dst,
        float* __restrict__ agg) {
    const int tid  = blockIdx.x * 256 + threadIdx.x;
    const int lane = threadIdx.x & 63;
    const int sub  = lane >> 4;
    const int q    = lane & 15;
    const int e    = (tid >> 6) * 4 + sub;
    if (e >= E_EDGES) return;
    const int s = src[e];
    const int d = dst[e];
    const float4 f  = *(const float4*)&feat[(size_t)e * HDIM + q * 4];
    const float4 hv = *(const float4*)&h[(size_t)s * HDIM + q * 4];
    float* p = &agg[(size_t)d * HDIM + q * 4];
    atomicAdd(p + 0, f.x * hv.x);
    atomicAdd(p + 1, f.y * hv.y);
    atomicAdd(p + 2, f.z * hv.z);
    atomicAdd(p + 3, f.w * hv.w);
}

extern "C" void kernel_launch(void* const* d_in, const int* in_sizes, int n_in,
                              void* d_out, int out_size, void* d_ws, size_t ws_size,
                              hipStream_t stream) {
    const float* h     = (const float*)d_in[0];
    const float* feat1 = (const float*)d_in[1];
    const float* feat2 = (const float*)d_in[2];
    const float* W1    = (const float*)d_in[3];
    const float* b1    = (const float*)d_in[4];
    const float* W2    = (const float*)d_in[5];
    const float* b2    = (const float*)d_in[6];
    const int*   src1  = (const int*)d_in[7];
    const int*   dst1  = (const int*)d_in[8];
    const int*   src2  = (const int*)d_in[9];
    const int*   dst2  = (const int*)d_in[10];

    float* out = (float*)d_out;

    // workspace layout
    float* a1   = (float*)d_ws;                   // N*H
    float* a2   = a1 + (size_t)N_NODES * HDIM;    // N*H
    int*   cnt1 = (int*)(a2 + (size_t)N_NODES * HDIM);
    int*   cnt2 = cnt1 + N_NODES;
    int*   off1 = cnt2 + N_NODES;
    int*   off2 = off1 + (N_NODES + 1);
    int*   cur1 = off2 + (N_NODES + 1);
    int*   cur2 = cur1 + N_NODES;
    int*   part = cur2 + N_NODES;                 // 2*NPART
    int*   pofs = part + 2 * NPART;               // 2*NPART
    int2*  pairs1 = (int2*)(pofs + 2 * NPART);
    int2*  pairs2 = pairs1 + E_EDGES;

    const size_t needed = (char*)(pairs2 + E_EDGES) - (char*)d_ws;

    const int eBlocks   = (E_EDGES + 255) / 256;
    const int segBlocks = (SEG_WAVES + 3) / 4;

    if (ws_size >= needed) {
        // ---- build CSR once (both relations per launch) ----
        hipMemsetAsync(cnt1, 0, 2 * (size_t)N_NODES * sizeof(int), stream);
        hist_kernel<<<dim3(eBlocks, 2), 256, 0, stream>>>(dst1, dst2, cnt1, cnt2);
        partial_kernel<<<dim3(NPART, 2), SCAN_BLK, 0, stream>>>(cnt1, cnt2, part);
        scanp_kernel<<<dim3(1, 2), 64, 0, stream>>>(part, pofs);
        fill_kernel<<<dim3(NPART, 2), SCAN_BLK, 0, stream>>>(
            cnt1, cnt2, pofs, off1, off2, cur1, cur2);
        scatter_kernel<<<dim3(eBlocks, 2), 256, 0, stream>>>(
            src1, dst1, src2, dst2, cur1, cur2, pairs1, pairs2);

        // ---- layer 1 ----
        agg_seg_kernel<<<dim3(segBlocks, 2), 256, 0, stream>>>(
            h, feat1, feat2, off1, off2, pairs1, pairs2, a1, a2);
        mlp_kernel<<<1024, 256, 0, stream>>>(h, a1, a2, W1, b1, out);

        // ---- layer 2 ----
        agg_seg_kernel<<<dim3(segBlocks, 2), 256, 0, stream>>>(
            out, feat1, feat2, off1, off2, pairs1, pairs2, a1, a2);
        mlp_kernel<<<1024, 256, 0, stream>>>(out, a1, a2, W2, b2, out);
    } else {
        // ---- fallback: atomic scatter path ----
        const size_t aggBytes = 2 * (size_t)N_NODES * HDIM * sizeof(float);
        const int atomBlocks = (E_EDGES + 15) / 16;

        hipMemsetAsync(d_ws, 0, aggBytes, stream);
        agg_atomic_kernel<<<atomBlocks, 256, 0, stream>>>(h, feat1, src1, dst1, a1);
        agg_atomic_kernel<<<atomBlocks, 256, 0, stream>>>(h, feat2, src2, dst2, a2);
        mlp_kernel<<<1024, 256, 0, stream>>>(h, a1, a2, W1, b1, out);

        hipMemsetAsync(d_ws, 0, aggBytes, stream);
        agg_atomic_kernel<<<atomBlocks, 256, 0, stream>>>(out, feat1, src1, dst1, a1);
        agg_atomic_kernel<<<atomBlocks, 256, 0, stream>>>(out, feat2, src2, dst2, a2);
        mlp_kernel<<<1024, 256, 0, stream>>>(out, a1, a2, W2, b2, out);
    }
}

// Round 2
// 838.898 us; speedup vs baseline: 1.1950x; 1.0616x over previous
//
#include <hip/hip_runtime.h>

#define N_NODES 50000
#define HDIM 64
#define E_EDGES 800000
#define SCAN_BLK 1024
#define NPART ((N_NODES + SCAN_BLK - 1) / SCAN_BLK)   // 49
#define CHUNK 128
#define SEG_WAVES ((E_EDGES + CHUNK - 1) / CHUNK)     // 6250 (E divides exactly)

__device__ __forceinline__ float lane_bcast(float v, int l) {
    return __int_as_float(__builtin_amdgcn_readlane(__float_as_int(v), l));
}

// ---------------- CSR build: histogram -> hierarchical scan -> scatter ---

__global__ void __launch_bounds__(256) hist_kernel(
        const int* __restrict__ dst1, const int* __restrict__ dst2,
        int* __restrict__ cnt1, int* __restrict__ cnt2) {
    const int* dst = blockIdx.y ? dst2 : dst1;
    int* cnt       = blockIdx.y ? cnt2 : cnt1;
    int e = blockIdx.x * 256 + threadIdx.x;
    if (e < E_EDGES) atomicAdd(&cnt[dst[e]], 1);
}

// per-1024-chunk partial sums (coalesced), grid (NPART, 2)
__global__ void __launch_bounds__(SCAN_BLK) partial_kernel(
        const int* __restrict__ cnt1, const int* __restrict__ cnt2,
        int* __restrict__ part) {
    const int* cnt = blockIdx.y ? cnt2 : cnt1;
    __shared__ int red[16];
    const int t = blockIdx.x * SCAN_BLK + threadIdx.x;
    int v = (t < N_NODES) ? cnt[t] : 0;
#pragma unroll
    for (int s = 32; s >= 1; s >>= 1) v += __shfl_xor(v, s);
    if ((threadIdx.x & 63) == 0) red[threadIdx.x >> 6] = v;
    __syncthreads();
    if (threadIdx.x == 0) {
        int ssum = 0;
#pragma unroll
        for (int i = 0; i < 16; ++i) ssum += red[i];
        part[blockIdx.y * NPART + blockIdx.x] = ssum;
    }
}

// exclusive scan of the NPART partials per relation; grid (1,2), 64 threads
__global__ void __launch_bounds__(64) scanp_kernel(
        const int* __restrict__ part, int* __restrict__ pofs) {
    const int r = blockIdx.y;
    const int t = threadIdx.x;
    int v = (t < NPART) ? part[r * NPART + t] : 0;
    const int orig = v;
#pragma unroll
    for (int s = 1; s < 64; s <<= 1) {
        int u = __shfl_up(v, s);
        if (t >= s) v += u;
    }
    if (t < NPART) pofs[r * NPART + t] = v - orig;   // exclusive prefix
}

// per-chunk scan + global offset; writes off and cur; grid (NPART, 2)
__global__ void __launch_bounds__(SCAN_BLK) fill_kernel(
        const int* __restrict__ cnt1, const int* __restrict__ cnt2,
        const int* __restrict__ pofs,
        int* __restrict__ off1, int* __restrict__ off2,
        int* __restrict__ cur1, int* __restrict__ cur2) {
    const int* cnt = blockIdx.y ? cnt2 : cnt1;
    int* off       = blockIdx.y ? off2 : off1;
    int* cur       = blockIdx.y ? cur2 : cur1;

    __shared__ int lds[SCAN_BLK];
    const int t = threadIdx.x;
    const int gid = blockIdx.x * SCAN_BLK + t;
    const int c = (gid < N_NODES) ? cnt[gid] : 0;
    lds[t] = c;
    __syncthreads();
    for (int s = 1; s < SCAN_BLK; s <<= 1) {
        int v = (t >= s) ? lds[t - s] : 0;
        __syncthreads();
        lds[t] += v;
        __syncthreads();
    }
    const int excl = lds[t] - c + pofs[blockIdx.y * NPART + blockIdx.x];
    if (gid < N_NODES) { off[gid] = excl; cur[gid] = excl; }
    if (gid == 0 && blockIdx.x == 0) off[N_NODES] = E_EDGES;
}

__global__ void __launch_bounds__(256) scatter_kernel(
        const int* __restrict__ src1, const int* __restrict__ dst1,
        const int* __restrict__ src2, const int* __restrict__ dst2,
        int* __restrict__ cur1, int* __restrict__ cur2,
        int2* __restrict__ pairs1, int2* __restrict__ pairs2) {
    const int* src = blockIdx.y ? src2 : src1;
    const int* dst = blockIdx.y ? dst2 : dst1;
    int* cur       = blockIdx.y ? cur2 : cur1;
    int2* pairs    = blockIdx.y ? pairs2 : pairs1;
    int e = blockIdx.x * 256 + threadIdx.x;
    if (e >= E_EDGES) return;
    int pos = atomicAdd(&cur[dst[e]], 1);
    pairs[pos] = make_int2(src[e], e);
}

// per-chunk first-node precompute: wstart[w] = first n with off[n] >= w*CHUNK
// grid ((SEG_WAVES+255)/256, 2) — hoists the binary search out of agg waves.
__global__ void __launch_bounds__(256) wstart_kernel(
        const int* __restrict__ off1, const int* __restrict__ off2,
        int* __restrict__ wstart1, int* __restrict__ wstart2) {
    const int* off = blockIdx.y ? off2 : off1;
    int* wstart    = blockIdx.y ? wstart2 : wstart1;
    const int w = blockIdx.x * 256 + threadIdx.x;
    if (w >= SEG_WAVES) return;
    const int C0 = w * CHUNK;
    int lo = 0, hi = N_NODES;
    while (lo < hi) {
        int mid = (lo + hi) >> 1;
        if (off[mid] < C0) lo = mid + 1; else hi = mid;
    }
    wstart[w] = lo;
}

// ---------------- aggregation: balanced chunks + float4 groups + LDS pairs
// Wave w owns all nodes whose segment STARTS in [w*CHUNK, (w+1)*CHUNK) and
// processes each fully (may overrun chunk end). Lanes: 4 groups of 16;
// group g handles edges s+g, s+g+4, ...; each group covers the full 64-col
// row as float4/lane (16B/lane in flight). Pairs staged in LDS (coalesced).

__global__ void __launch_bounds__(256) agg_seg_kernel(
        const float* __restrict__ h,
        const float* __restrict__ feat1, const float* __restrict__ feat2,
        const int* __restrict__ off1, const int* __restrict__ off2,
        const int2* __restrict__ pairs1, const int2* __restrict__ pairs2,
        const int* __restrict__ wstart1, const int* __restrict__ wstart2,
        float* __restrict__ a1, float* __restrict__ a2) {
    const float* feat  = blockIdx.y ? feat2   : feat1;
    const int* off     = blockIdx.y ? off2    : off1;
    const int2* pairs  = blockIdx.y ? pairs2  : pairs1;
    const int* wstart  = blockIdx.y ? wstart2 : wstart1;
    float* agg         = blockIdx.y ? a2      : a1;

    __shared__ int2 plds[4][CHUNK];   // 4 KB/block, per-wave slab (no barrier)

    const int tid  = threadIdx.x;
    const int lane = tid & 63;
    const int wsl  = tid >> 6;      // wave slot in block
    const int g    = lane >> 4;     // edge subgroup 0..3
    const int q    = lane & 15;     // float4 column slot
    const int wv   = blockIdx.x * 4 + wsl;
    if (wv >= SEG_WAVES) return;

    const int C0 = wv * CHUNK;
    int C1 = C0 + CHUNK;
    if (C1 >= E_EDGES) C1 = E_EDGES + 1;  // last wave owns trailing deg-0 nodes

    // stage this wave's 128 pairs (coalesced 8B loads; same-wave LDS use,
    // ordering via lgkmcnt — no __syncthreads needed, slabs are private)
    plds[wsl][lane]      = pairs[C0 + lane];
    plds[wsl][lane + 64] = pairs[C0 + lane + 64];

    int n = wstart[wv];
    if (n >= N_NODES) return;

    int s = off[n];
    while (s >= C0 && s < C1) {
        const int e = off[n + 1];
        float4 acc = make_float4(0.f, 0.f, 0.f, 0.f);
#pragma unroll 2
        for (int i = s + g; i < e; i += 4) {
            int2 p;
            if (i < C0 + CHUNK) p = plds[wsl][i - C0];  // broadcast read
            else                p = pairs[i];           // rare overrun
            const float4 f  = *(const float4*)&feat[((size_t)p.y << 6) + (q << 2)];
            const float4 hv = *(const float4*)&h[((size_t)p.x << 6) + (q << 2)];
            acc.x = fmaf(f.x, hv.x, acc.x);
            acc.y = fmaf(f.y, hv.y, acc.y);
            acc.z = fmaf(f.z, hv.z, acc.z);
            acc.w = fmaf(f.w, hv.w, acc.w);
        }
        // combine the 4 groups (lanes differing in bits 4 and 5)
        acc.x += __shfl_xor(acc.x, 16); acc.y += __shfl_xor(acc.y, 16);
        acc.z += __shfl_xor(acc.z, 16); acc.w += __shfl_xor(acc.w, 16);
        acc.x += __shfl_xor(acc.x, 32); acc.y += __shfl_xor(acc.y, 32);
        acc.z += __shfl_xor(acc.z, 32); acc.w += __shfl_xor(acc.w, 32);
        if (lane < 16) {
            *(float4*)&agg[((size_t)n << 6) + (q << 2)] = acc;
        }
        if (++n >= N_NODES) break;
        s = e;   // off[n] == previous off[n+1]
    }
}

// ---------------- fused linear + relu + residual (readlane, W in VGPRs) --

__global__ void __launch_bounds__(256, 2) mlp_kernel(
        const float* __restrict__ h_in,
        const float* __restrict__ a1,
        const float* __restrict__ a2,
        const float* __restrict__ W,
        const float* __restrict__ b,
        float* __restrict__ h_out) {
    const int lane = threadIdx.x & 63;

    float w1r[HDIM], w2r[HDIM];          // W[k][lane] — 128 VGPRs, static idx
#pragma unroll
    for (int k = 0; k < HDIM; ++k) w1r[k] = W[k * HDIM + lane];
#pragma unroll
    for (int k = 0; k < HDIM; ++k) w2r[k] = W[(HDIM + k) * HDIM + lane];
    const float bias = b[lane];

    const int wv = blockIdx.x * 4 + (threadIdx.x >> 6);
    const int stride = gridDim.x * 4;
    for (int node = wv; node < N_NODES; node += stride) {
        const size_t base = (size_t)node << 6;
        const float x1 = a1[base + lane];
        const float x2 = a2[base + lane];
        float acc1 = bias, acc2 = 0.f;
#pragma unroll
        for (int k = 0; k < HDIM; ++k) {
            acc1 = fmaf(lane_bcast(x1, k), w1r[k], acc1);   // two independent
            acc2 = fmaf(lane_bcast(x2, k), w2r[k], acc2);   // fma chains
        }
        const float r = acc1 + acc2;
        h_out[base + lane] = h_in[base + lane] + fmaxf(r, 0.f);
    }
}

// ---------------- fallback (atomic path, if ws too small) ----------------

__global__ void __launch_bounds__(256) agg_atomic_kernel(
        const float* __restrict__ h,
        const float* __restrict__ feat,
        const int* __restrict__ src,
        const int* __restrict__ dst,
        float* __restrict__ agg) {
    const int tid  = blockIdx.x * 256 + threadIdx.x;
    const int lane = threadIdx.x & 63;
    const int sub  = lane >> 4;
    const int q    = lane & 15;
    const int e    = (tid >> 6) * 4 + sub;
    if (e >= E_EDGES) return;
    const int s = src[e];
    const int d = dst[e];
    const float4 f  = *(const float4*)&feat[(size_t)e * HDIM + q * 4];
    const float4 hv = *(const float4*)&h[(size_t)s * HDIM + q * 4];
    float* p = &agg[(size_t)d * HDIM + q * 4];
    atomicAdd(p + 0, f.x * hv.x);
    atomicAdd(p + 1, f.y * hv.y);
    atomicAdd(p + 2, f.z * hv.z);
    atomicAdd(p + 3, f.w * hv.w);
}

extern "C" void kernel_launch(void* const* d_in, const int* in_sizes, int n_in,
                              void* d_out, int out_size, void* d_ws, size_t ws_size,
                              hipStream_t stream) {
    const float* h     = (const float*)d_in[0];
    const float* feat1 = (const float*)d_in[1];
    const float* feat2 = (const float*)d_in[2];
    const float* W1    = (const float*)d_in[3];
    const float* b1    = (const float*)d_in[4];
    const float* W2    = (const float*)d_in[5];
    const float* b2    = (const float*)d_in[6];
    const int*   src1  = (const int*)d_in[7];
    const int*   dst1  = (const int*)d_in[8];
    const int*   src2  = (const int*)d_in[9];
    const int*   dst2  = (const int*)d_in[10];

    float* out = (float*)d_out;

    // workspace layout
    float* a1   = (float*)d_ws;                   // N*H
    float* a2   = a1 + (size_t)N_NODES * HDIM;    // N*H
    int*   cnt1 = (int*)(a2 + (size_t)N_NODES * HDIM);
    int*   cnt2 = cnt1 + N_NODES;
    int*   off1 = cnt2 + N_NODES;
    int*   off2 = off1 + (N_NODES + 1);
    int*   cur1 = off2 + (N_NODES + 1);
    int*   cur2 = cur1 + N_NODES;
    int*   part = cur2 + N_NODES;                 // 2*NPART
    int*   pofs = part + 2 * NPART;               // 2*NPART
    int*   wstart1 = pofs + 2 * NPART;            // SEG_WAVES
    int*   wstart2 = wstart1 + SEG_WAVES;         // SEG_WAVES
    int2*  pairs1 = (int2*)(wstart2 + SEG_WAVES);
    int2*  pairs2 = pairs1 + E_EDGES;

    const size_t needed = (char*)(pairs2 + E_EDGES) - (char*)d_ws;

    const int eBlocks   = (E_EDGES + 255) / 256;
    const int segBlocks = (SEG_WAVES + 3) / 4;
    const int wsBlocks  = (SEG_WAVES + 255) / 256;

    if (ws_size >= needed) {
        // ---- build CSR once (both relations per launch) ----
        hipMemsetAsync(cnt1, 0, 2 * (size_t)N_NODES * sizeof(int), stream);
        hist_kernel<<<dim3(eBlocks, 2), 256, 0, stream>>>(dst1, dst2, cnt1, cnt2);
        partial_kernel<<<dim3(NPART, 2), SCAN_BLK, 0, stream>>>(cnt1, cnt2, part);
        scanp_kernel<<<dim3(1, 2), 64, 0, stream>>>(part, pofs);
        fill_kernel<<<dim3(NPART, 2), SCAN_BLK, 0, stream>>>(
            cnt1, cnt2, pofs, off1, off2, cur1, cur2);
        scatter_kernel<<<dim3(eBlocks, 2), 256, 0, stream>>>(
            src1, dst1, src2, dst2, cur1, cur2, pairs1, pairs2);
        wstart_kernel<<<dim3(wsBlocks, 2), 256, 0, stream>>>(
            off1, off2, wstart1, wstart2);

        // ---- layer 1 ----
        agg_seg_kernel<<<dim3(segBlocks, 2), 256, 0, stream>>>(
            h, feat1, feat2, off1, off2, pairs1, pairs2, wstart1, wstart2, a1, a2);
        mlp_kernel<<<1024, 256, 0, stream>>>(h, a1, a2, W1, b1, out);

        // ---- layer 2 ----
        agg_seg_kernel<<<dim3(segBlocks, 2), 256, 0, stream>>>(
            out, feat1, feat2, off1, off2, pairs1, pairs2, wstart1, wstart2, a1, a2);
        mlp_kernel<<<1024, 256, 0, stream>>>(out, a1, a2, W2, b2, out);
    } else {
        // ---- fallback: atomic scatter path ----
        const size_t aggBytes = 2 * (size_t)N_NODES * HDIM * sizeof(float);
        const int atomBlocks = (E_EDGES + 15) / 16;

        hipMemsetAsync(d_ws, 0, aggBytes, stream);
        agg_atomic_kernel<<<atomBlocks, 256, 0, stream>>>(h, feat1, src1, dst1, a1);
        agg_atomic_kernel<<<atomBlocks, 256, 0, stream>>>(h, feat2, src2, dst2, a2);
        mlp_kernel<<<1024, 256, 0, stream>>>(h, a1, a2, W1, b1, out);

        hipMemsetAsync(d_ws, 0, aggBytes, stream);
        agg_atomic_kernel<<<atomBlocks, 256, 0, stream>>>(out, feat1, src1, dst1, a1);
        agg_atomic_kernel<<<atomBlocks, 256, 0, stream>>>(out, feat2, src2, dst2, a2);
        mlp_kernel<<<1024, 256, 0, stream>>>(out, a1, a2, W2, b2, out);
    }
}